// Round 18
// baseline (36.927 us; speedup 1.0000x reference)
//
#include <hip/hip_runtime.h>

#define L 512
#define LMASK 511
#define HID 32

constexpr int THREADS        = 256;
constexpr int ROWS_PER_BLOCK = 2;
constexpr int BLOCKS_PER_B   = L / ROWS_PER_BLOCK;   // 256
constexpr int NTAB           = 4096;                 // 1/64 cells, z' in [-32,32]
constexpr int GT             = 5;                    // table groups (20 h)
constexpr int NPAIR_E        = 6;                    // exp pairs (12 h)

constexpr float MAGIC = 8388608.0f;                  // 2^23
constexpr float BIASB = 8194.0f;                     // 256*32 + 2 (half-cell center)

#define OPAQUE(v) asm volatile("" : "+v"(v))

// R18: R17's issue/trans/consume pipeline, but the exp phase is LDS-SILENT:
// all exp-pair weights live in VGPRs (asm-opacified against remat). The 16
// outstanding table gathers now genuinely resolve under the trans burst —
// previously every phase re-read weights from LDS, and their lgkmcnt waits
// drained the gathers first (the hidden serializer in R7/R10/R11/R13/R17).
__global__ __launch_bounds__(THREADS)
void site_kernel(const float* __restrict__ x,
                 const float* __restrict__ W1,
                 const float* __restrict__ b1,
                 const float* __restrict__ W2,
                 float* __restrict__ partial) {
    __shared__ __align__(16) float tab_s[NTAB];      // T(z')=1/(1+2^z'), nearest
    __shared__ __align__(16) float zw_s[GT * 16];    // table groups {wa4 wb4 wc4 w04}
    __shared__ __align__(16) float w2t_s[GT * 4];    // table-path w2
    __shared__ __align__(16) float ew_s[NPAIR_E * 8];// exp pairs {wa01 wb01 wc01 w001}
    __shared__ __align__(16) float ew2_s[NPAIR_E * 2];

    const int t = threadIdx.x;
    const float Ke = 2.8853900817779268f;            // 2*log2(e)

    if (t < HID) {
        if (t < 4 * GT) {                            // table-path h
            const float K256 = 256.0f * Ke;
            const int g = t >> 2, q = t & 3;
            zw_s[g * 16 +  0 + q] = K256 * W1[t * 3 + 0];
            zw_s[g * 16 +  4 + q] = K256 * W1[t * 3 + 1];
            zw_s[g * 16 +  8 + q] = K256 * W1[t * 3 + 2];
            zw_s[g * 16 + 12 + q] = fmaf(K256, b1[t], BIASB + MAGIC);
            w2t_s[t] = -2.0f * W2[t];                // tanh = 1 - 2*T
        } else {                                     // exp-path h
            const int e = t - 4 * GT, p = e >> 1, q = e & 1;
            ew_s[p * 8 + 0 + q] = Ke * W1[t * 3 + 0];
            ew_s[p * 8 + 2 + q] = Ke * W1[t * 3 + 1];
            ew_s[p * 8 + 4 + q] = Ke * W1[t * 3 + 2];
            ew_s[p * 8 + 6 + q] = Ke * b1[t];
            ew2_s[p * 2 + q]    = -2.0f * W2[t];
        }
    }
    for (int i = t; i < NTAB; i += THREADS) {
        const float zp = fmaf((float)i, 0.015625f, -32.001953125f);
        tab_s[i] = __builtin_amdgcn_rcpf(1.0f + __builtin_amdgcn_exp2f(zp));
    }
    __syncthreads();

    // ---- Exp-pair weights -> VGPRs, opacified (no remat, no LDS re-reads) ----
    float ewr[NPAIR_E * 8];                          // 48
#pragma unroll
    for (int i = 0; i < NPAIR_E * 2; ++i) {
        const float4 v = *(const float4*)&ew_s[i * 4];
        ewr[i * 4 + 0] = v.x; ewr[i * 4 + 1] = v.y;
        ewr[i * 4 + 2] = v.z; ewr[i * 4 + 3] = v.w;
    }
    float e2r[NPAIR_E * 2];                          // 12
#pragma unroll
    for (int i = 0; i < 3; ++i) {
        const float4 v = *(const float4*)&ew2_s[i * 4];
        e2r[i * 4 + 0] = v.x; e2r[i * 4 + 1] = v.y;
        e2r[i * 4 + 2] = v.z; e2r[i * 4 + 3] = v.w;
    }
#pragma unroll
    for (int i = 0; i < NPAIR_E * 8; ++i) OPAQUE(ewr[i]);
#pragma unroll
    for (int i = 0; i < NPAIR_E * 2; ++i) OPAQUE(e2r[i]);

    const int blk = blockIdx.x;
    const int b   = blk >> 8;                        // / BLOCKS_PER_B
    const int i0  = (blk & (BLOCKS_PER_B - 1)) * ROWS_PER_BLOCK;
    const float* __restrict__ xb = x + (size_t)b * (L * L);

    // Features for 4 sites: rows i0,i0+1, cols t and t+256.
    float F0[4], F1[4], F2[4];
#pragma unroll
    for (int g = 0; g < 2; ++g) {
        const int j  = t + g * THREADS;
        const int jm = (j + LMASK) & LMASK, jp = (j + 1) & LMASK;

        float cc[4];                                 // center col, rows i0-1..i0+2
#pragma unroll
        for (int r = 0; r < 4; ++r) {
            const int i = (i0 + r - 1 + L) & LMASK;
            cc[r] = xb[i * L + j];
        }
#pragma unroll
        for (int s = 0; s < 2; ++s) {
            const int i   = i0 + s;
            const float lf = xb[i * L + jm];
            const float rg = xb[i * L + jp];
            const float c  = cc[s + 1];
            const float lr = lf + rg;                // == sx
            const float x1 = lr + cc[s] + cc[s + 2];
            const int k = g * 2 + s;
            F0[k] = c * c;  F1[k] = x1 * c;  F2[k] = lr * c;
        }
    }

    float acc[4] = {0.f, 0.f, 0.f, 0.f};
    const char* __restrict__ tb = (const char*)tab_s;

    int   offs[16];
    float tt[16];

    // Phase 1 (pre-gather): zw + w2 LDS reads, address math, issue 16 gathers.
    auto taddr_load = [&](const int gq, float4& w2v) {
        const float4 wa = *(const float4*)&zw_s[gq * 16 + 0];
        const float4 wb = *(const float4*)&zw_s[gq * 16 + 4];
        const float4 wc = *(const float4*)&zw_s[gq * 16 + 8];
        const float4 w0 = *(const float4*)&zw_s[gq * 16 + 12];
        w2v = *(const float4*)&w2t_s[gq * 4];
#pragma unroll
        for (int q = 0; q < 4; ++q) {
            const float waq = ((const float*)&wa)[q];
            const float wbq = ((const float*)&wb)[q];
            const float wcq = ((const float*)&wc)[q];
            const float w0q = ((const float*)&w0)[q];
#pragma unroll
            for (int s = 0; s < 4; ++s) {
                const float uu = fmaf(F0[s], waq, fmaf(F1[s], wbq, fmaf(F2[s], wcq, w0q)));
                offs[q * 4 + s] = __float_as_int(uu) & 0x3FFC;
            }
        }
#pragma unroll
        for (int i = 0; i < 16; ++i)
            tt[i] = *reinterpret_cast<const float*>(tb + offs[i]);
        __builtin_amdgcn_sched_barrier(0);           // pin gathers before trans burst
    };
    // Phase 2: exp pair — REGISTER-ONLY (no LDS): gathers resolve underneath.
    auto epair = [&](const int p) {
        const float wa0 = ewr[p * 8 + 0], wa1 = ewr[p * 8 + 1];
        const float wb0 = ewr[p * 8 + 2], wb1 = ewr[p * 8 + 3];
        const float wc0 = ewr[p * 8 + 4], wc1 = ewr[p * 8 + 5];
        const float w00 = ewr[p * 8 + 6], w01 = ewr[p * 8 + 7];
        const float w2x = e2r[p * 2 + 0], w2y = e2r[p * 2 + 1];
#pragma unroll
        for (int s = 0; s < 4; ++s) {
            const float z0 = fmaf(F0[s], wa0, fmaf(F1[s], wb0, fmaf(F2[s], wc0, w00)));
            const float z1 = fmaf(F0[s], wa1, fmaf(F1[s], wb1, fmaf(F2[s], wc1, w01)));
            const float d0 = 1.0f + __builtin_amdgcn_exp2f(z0);
            const float d1 = 1.0f + __builtin_amdgcn_exp2f(z1);
            const float nm = fmaf(w2x, d1, w2y * d0);   // w2a/d0 + w2b/d1
            const float rr = __builtin_amdgcn_rcpf(d0 * d1);
            acc[s] = fmaf(nm, rr, acc[s]);
        }
    };
    // Phase 3: consume gathered table values (single lgkmcnt drain).
    auto tcons = [&](const float4 w2v) {
#pragma unroll
        for (int q = 0; q < 4; ++q) {
            const float w2q = ((const float*)&w2v)[q];
#pragma unroll
            for (int s = 0; s < 4; ++s)
                acc[s] = fmaf(w2q, tt[q * 4 + s], acc[s]);
        }
    };

    float4 w2v;
    taddr_load(0, w2v); epair(0); tcons(w2v);
    taddr_load(1, w2v); epair(1); tcons(w2v);
    taddr_load(2, w2v); epair(2); tcons(w2v);
    taddr_load(3, w2v); epair(3); tcons(w2v);
    taddr_load(4, w2v); epair(4); tcons(w2v);
    epair(5);

    float a = (acc[0] + acc[1]) + (acc[2] + acc[3]);
#pragma unroll
    for (int off = 32; off > 0; off >>= 1)
        a += __shfl_down(a, off, 64);

    __shared__ float wsum[THREADS / 64];
    const int wid = t >> 6, lane = t & 63;
    if (lane == 0) wsum[wid] = a;
    __syncthreads();
    if (t == 0)
        partial[blk] = (wsum[0] + wsum[1]) + (wsum[2] + wsum[3]);
}

// Deterministic fixed-order reduction + folded tanh constant.
__global__ __launch_bounds__(256)
void reduce_kernel(const float* __restrict__ partial,
                   const float* __restrict__ W2,
                   const float* __restrict__ b2,
                   float* __restrict__ out) {
    const int b = blockIdx.x, t = threadIdx.x;
    const float NS = (float)(L * L);                 // 262144 sites per config

    float v = partial[b * BLOCKS_PER_B + t];
    if (t < HID) v += NS * W2[t];                    // + L^2 * sum_h W2[h]
    if (t == 0)  v += NS * b2[0];                    // + L^2 * b2

#pragma unroll
    for (int off = 32; off > 0; off >>= 1)
        v += __shfl_down(v, off, 64);

    __shared__ float ws4[4];
    if ((t & 63) == 0) ws4[t >> 6] = v;
    __syncthreads();
    if (t == 0) out[b] = (ws4[0] + ws4[1]) + (ws4[2] + ws4[3]);
}

extern "C" void kernel_launch(void* const* d_in, const int* in_sizes, int n_in,
                              void* d_out, int out_size, void* d_ws, size_t ws_size,
                              hipStream_t stream) {
    const float* x  = (const float*)d_in[0];
    const float* W1 = (const float*)d_in[1];
    const float* b1 = (const float*)d_in[2];
    const float* W2 = (const float*)d_in[3];
    const float* b2 = (const float*)d_in[4];
    float* out      = (float*)d_out;
    float* partial  = (float*)d_ws;                  // 4096 floats

    const int B = in_sizes[0] / (L * L);             // 16

    site_kernel<<<B * BLOCKS_PER_B, THREADS, 0, stream>>>(x, W1, b1, W2, partial);
    reduce_kernel<<<B, 256, 0, stream>>>(partial, W2, b2, out);
}

// Round 19
// 32.214 us; speedup vs baseline: 1.1463x; 1.1463x over previous
//
#include <hip/hip_runtime.h>

#define L 512
#define LMASK 511
#define HID 32

constexpr int THREADS        = 256;
constexpr int ROWS_PER_BLOCK = 4;
constexpr int BLOCKS_PER_B   = L / ROWS_PER_BLOCK;   // 128
constexpr int NTAB           = 2048;                 // cells of 1/64 z', z' in [-16,16]
constexpr int GT             = 5;                    // table groups (20 h)
constexpr int NPAIR_E        = 6;                    // exp pairs (12 h)

// Magic addressing: mantissa of (256*z' + 4098 + 2^23) = byte offset into table
constexpr float MAGIC   = 8388608.0f;                // 2^23
constexpr float CLAMPLO = 8388608.0f;                // cell 0
constexpr float CLAMPHI = 8396796.0f;                // 2^23 + 4*2047

// R19 = verbatim revert to R11 (best verified: 32.34 us, absmax 0).
// Fine-grained straight-line interleave of table groups and exp pairs.
__global__ __launch_bounds__(THREADS)
void site_kernel(const float* __restrict__ x,
                 const float* __restrict__ W1,
                 const float* __restrict__ b1,
                 const float* __restrict__ W2,
                 float* __restrict__ partial) {
    __shared__ __align__(16) float tab_s[NTAB];      // T(z')=1/(1+2^z'), nearest
    __shared__ __align__(16) float zw_s[GT * 16];    // table groups {wa4 wb4 wc4 w04}
    __shared__ __align__(16) float w2t_s[GT * 4];    // table-path w2
    __shared__ __align__(16) float ew_s[NPAIR_E * 8];// exp pairs {wa01 wb01 wc01 w001}
    __shared__ __align__(8)  float ew2_s[NPAIR_E * 2];

    const int t = threadIdx.x;
    const float Ke = 2.8853900817779268f;            // 2*log2(e)

    if (t < HID) {
        if (t < 4 * GT) {                            // table-path h
            const float K256 = 256.0f * Ke;
            const int g = t >> 2, q = t & 3;
            zw_s[g * 16 +  0 + q] = K256 * W1[t * 3 + 0];
            zw_s[g * 16 +  4 + q] = K256 * W1[t * 3 + 1];
            zw_s[g * 16 +  8 + q] = K256 * W1[t * 3 + 2];
            zw_s[g * 16 + 12 + q] = fmaf(K256, b1[t], 4098.0f + MAGIC);
            w2t_s[t] = -2.0f * W2[t];                // tanh = 1 - 2*T
        } else {                                     // exp-path h
            const int e = t - 4 * GT, p = e >> 1, q = e & 1;
            ew_s[p * 8 + 0 + q] = Ke * W1[t * 3 + 0];
            ew_s[p * 8 + 2 + q] = Ke * W1[t * 3 + 1];
            ew_s[p * 8 + 4 + q] = Ke * W1[t * 3 + 2];
            ew_s[p * 8 + 6 + q] = Ke * b1[t];
            ew2_s[p * 2 + q]    = -2.0f * W2[t];
        }
    }
    // Table entry i: T at the true center of cell i (magic mapping).
    for (int i = t; i < NTAB; i += THREADS) {
        const float zp = fmaf((float)i, 0.015625f, -16.001953125f);
        tab_s[i] = __builtin_amdgcn_rcpf(1.0f + __builtin_amdgcn_exp2f(zp));
    }
    __syncthreads();

    const int blk = blockIdx.x;
    const int b   = blk >> 7;                        // / BLOCKS_PER_B
    const int i0  = (blk & (BLOCKS_PER_B - 1)) * ROWS_PER_BLOCK;
    const float* __restrict__ xb = x + (size_t)b * (L * L);

    // Features for 8 sites: rows i0..i0+3, cols t and t+256.
    float F0[8], F1[8], F2[8];
#pragma unroll
    for (int g = 0; g < 2; ++g) {
        const int j  = t + g * THREADS;
        const int jm = (j + LMASK) & LMASK, jp = (j + 1) & LMASK;

        float cc[6];                                 // center col, rows i0-1..i0+4
#pragma unroll
        for (int r = 0; r < 6; ++r) {
            const int i = (i0 + r - 1 + L) & LMASK;
            cc[r] = xb[i * L + j];
        }
#pragma unroll
        for (int s = 0; s < 4; ++s) {
            const int i   = i0 + s;
            const float lf = xb[i * L + jm];
            const float rg = xb[i * L + jp];
            const float c  = cc[s + 1];
            const float lr = lf + rg;                // == sx
            const float x1 = lr + cc[s] + cc[s + 2];
            const int k = g * 4 + s;
            F0[k] = c * c;  F1[k] = x1 * c;  F2[k] = lr * c;
        }
    }

    float acc[8] = {0.f, 0.f, 0.f, 0.f, 0.f, 0.f, 0.f, 0.f};
    const char* __restrict__ tb = (const char*)tab_s;

    // One table group (4 h x 8 sites): LDS-gather pipe.
    auto tgroup = [&](const int gq) {
        const float4 wa  = *(const float4*)&zw_s[gq * 16 + 0];
        const float4 wb  = *(const float4*)&zw_s[gq * 16 + 4];
        const float4 wc  = *(const float4*)&zw_s[gq * 16 + 8];
        const float4 w0  = *(const float4*)&zw_s[gq * 16 + 12];
        const float4 w2v = *(const float4*)&w2t_s[gq * 4];
#pragma unroll
        for (int q = 0; q < 4; ++q) {
            const float waq = ((const float*)&wa)[q];
            const float wbq = ((const float*)&wb)[q];
            const float wcq = ((const float*)&wc)[q];
            const float w0q = ((const float*)&w0)[q];
            const float w2q = ((const float*)&w2v)[q];
#pragma unroll
            for (int s = 0; s < 8; ++s) {
                const float uu = fmaf(F0[s], waq, fmaf(F1[s], wbq, fmaf(F2[s], wcq, w0q)));
                const float uc = __builtin_amdgcn_fmed3f(uu, CLAMPLO, CLAMPHI);
                const int  off = __float_as_int(uc) & 0x007FFFFC;
                const float y  = *reinterpret_cast<const float*>(tb + off);
                acc[s] = fmaf(w2q, y, acc[s]);
            }
        }
    };
    // One exp pair (2 h x 8 sites): VALU + trans issue-port work.
    auto epair = [&](const int p) {
        const float4 e0 = *(const float4*)&ew_s[p * 8 + 0];  // wa0 wa1 wb0 wb1
        const float4 e1 = *(const float4*)&ew_s[p * 8 + 4];  // wc0 wc1 w00 w01
        const float2 w2p = *(const float2*)&ew2_s[p * 2];
        const float wa0 = e0.x, wa1 = e0.y, wb0 = e0.z, wb1 = e0.w;
        const float wc0 = e1.x, wc1 = e1.y, w00 = e1.z, w01 = e1.w;
#pragma unroll
        for (int s = 0; s < 8; ++s) {
            float z0 = fmaf(F0[s], wa0, fmaf(F1[s], wb0, fmaf(F2[s], wc0, w00)));
            float z1 = fmaf(F0[s], wa1, fmaf(F1[s], wb1, fmaf(F2[s], wc1, w01)));
            z0 = __builtin_amdgcn_fmed3f(z0, -30.0f, 30.0f);
            z1 = __builtin_amdgcn_fmed3f(z1, -30.0f, 30.0f);
            const float d0 = 1.0f + __builtin_amdgcn_exp2f(z0);
            const float d1 = 1.0f + __builtin_amdgcn_exp2f(z1);
            const float nm = fmaf(w2p.x, d1, w2p.y * d0); // w2a/d0+w2b/d1
            const float rr = __builtin_amdgcn_rcpf(d0 * d1);
            acc[s] = fmaf(nm, rr, acc[s]);
        }
    };

    // Fine interleave, single basic block: gather latency hides under exp work.
    tgroup(0); epair(0);
    tgroup(1); epair(1);
    tgroup(2); epair(2);
    tgroup(3); epair(3);
    tgroup(4); epair(4); epair(5);

    float a = ((acc[0] + acc[1]) + (acc[2] + acc[3]))
            + ((acc[4] + acc[5]) + (acc[6] + acc[7]));
#pragma unroll
    for (int off = 32; off > 0; off >>= 1)
        a += __shfl_down(a, off, 64);

    __shared__ float wsum[THREADS / 64];
    const int wid = t >> 6, lane = t & 63;
    if (lane == 0) wsum[wid] = a;
    __syncthreads();
    if (t == 0)
        partial[blk] = (wsum[0] + wsum[1]) + (wsum[2] + wsum[3]);
}

// Deterministic fixed-order reduction + folded tanh constant.
__global__ __launch_bounds__(128)
void reduce_kernel(const float* __restrict__ partial,
                   const float* __restrict__ W2,
                   const float* __restrict__ b2,
                   float* __restrict__ out) {
    const int b = blockIdx.x, t = threadIdx.x;
    const float NS = (float)(L * L);                 // 262144 sites per config

    float v = partial[b * BLOCKS_PER_B + t];
    if (t < HID) v += NS * W2[t];                    // + L^2 * sum_h W2[h]
    if (t == 0)  v += NS * b2[0];                    // + L^2 * b2

#pragma unroll
    for (int off = 32; off > 0; off >>= 1)
        v += __shfl_down(v, off, 64);

    __shared__ float ws2[2];
    if ((t & 63) == 0) ws2[t >> 6] = v;
    __syncthreads();
    if (t == 0) out[b] = ws2[0] + ws2[1];
}

extern "C" void kernel_launch(void* const* d_in, const int* in_sizes, int n_in,
                              void* d_out, int out_size, void* d_ws, size_t ws_size,
                              hipStream_t stream) {
    const float* x  = (const float*)d_in[0];
    const float* W1 = (const float*)d_in[1];
    const float* b1 = (const float*)d_in[2];
    const float* W2 = (const float*)d_in[3];
    const float* b2 = (const float*)d_in[4];
    float* out      = (float*)d_out;
    float* partial  = (float*)d_ws;                  // 2048 floats

    const int B = in_sizes[0] / (L * L);             // 16

    site_kernel<<<B * BLOCKS_PER_B, THREADS, 0, stream>>>(x, W1, b1, W2, partial);
    reduce_kernel<<<B, 128, 0, stream>>>(partial, W2, b2, out);
}